// Round 7
// baseline (1159.347 us; speedup 1.0000x reference)
//
#include <hip/hip_runtime.h>
#include <hip/hip_bf16.h>
#include <stdint.h>

typedef __attribute__((ext_vector_type(4))) float f32x4;
typedef __attribute__((ext_vector_type(8))) __bf16 bf16x8;
typedef __attribute__((ext_vector_type(4))) unsigned short u16x4;
typedef unsigned short u16;

#define NTOK 8192
#define DDIM 1024
#define FDIM 4096
#define NEXP 8

// ---- workspace layout (bytes) ----
#define WS_XB    0ull
#define WS_W1T   (16777216ull)
#define WS_W2T   (WS_W1T + 134217728ull)
#define WS_ACT   (WS_W2T + 67108864ull)
#define WS_LIST  (WS_ACT + 142606336ull)
#define WS_PAIRW (WS_LIST + 262144ull)
#define WS_CNT   (WS_PAIRW + 262144ull)
#define WS_SUMP  (WS_CNT + 32ull)
#define WS_PAD   (WS_SUMP + 32ull)
#define WS_OFF   (WS_PAD + 32ull)
#define WS_T1E   (WS_OFF + 32ull)
#define WS_T1R   (WS_T1E + 512ull)
#define WS_T2E   (WS_T1R + 512ull)
#define WS_T2R   (WS_T2E + 1024ull)

static __device__ __forceinline__ u16 bf16rne(float f) {
  union { float f; uint32_t u; } c; c.f = f;
  return (u16)((c.u + 0x7FFFu + ((c.u >> 16) & 1u)) >> 16);
}

static __device__ __forceinline__ void load_lds16(const void* g, void* l) {
  __builtin_amdgcn_global_load_lds((const __attribute__((address_space(1))) void*)g,
                                   (__attribute__((address_space(3))) void*)l, 16, 0, 0);
}

// ---------------- gating + routing + x->bf16 ----------------
__global__ __launch_bounds__(256) void gate_kernel(
    const float* __restrict__ x, const float* __restrict__ gw,
    const float* __restrict__ gb, u16* __restrict__ xb,
    int* __restrict__ cnt, float* __restrict__ sump,
    int* __restrict__ list, float* __restrict__ pairw) {
  const int tid = threadIdx.x;
  const int lane = tid & 63;
  const int wv = tid >> 6;
  const int t = blockIdx.x * 4 + wv;

  __shared__ float sp[8];
  if (tid < 8) sp[tid] = 0.f;
  __syncthreads();

  float acc[8] = {0.f,0.f,0.f,0.f,0.f,0.f,0.f,0.f};
  const float4* x4 = (const float4*)x + (size_t)t * 256;
  u16x4* xb4 = (u16x4*)xb + (size_t)t * 256;
  #pragma unroll
  for (int it = 0; it < 4; ++it) {
    const float4 xv = x4[it * 64 + lane];
    u16x4 bv;
    bv[0] = bf16rne(xv.x); bv[1] = bf16rne(xv.y);
    bv[2] = bf16rne(xv.z); bv[3] = bf16rne(xv.w);
    xb4[it * 64 + lane] = bv;
    const int d0 = (it * 64 + lane) * 4;
    #pragma unroll
    for (int j = 0; j < 4; ++j) {
      const float xs = (j == 0) ? xv.x : ((j == 1) ? xv.y : ((j == 2) ? xv.z : xv.w));
      const float* g = gw + (size_t)(d0 + j) * 8;
      #pragma unroll
      for (int e2 = 0; e2 < 8; ++e2) acc[e2] += xs * g[e2];
    }
  }
  #pragma unroll
  for (int e2 = 0; e2 < 8; ++e2) {
    float v = acc[e2];
    v += __shfl_xor(v, 1);  v += __shfl_xor(v, 2);  v += __shfl_xor(v, 4);
    v += __shfl_xor(v, 8);  v += __shfl_xor(v, 16); v += __shfl_xor(v, 32);
    acc[e2] = v;
  }
  float p[8]; float mx = -1e30f;
  #pragma unroll
  for (int e2 = 0; e2 < 8; ++e2) { p[e2] = acc[e2] + gb[e2]; mx = fmaxf(mx, p[e2]); }
  float s = 0.f;
  #pragma unroll
  for (int e2 = 0; e2 < 8; ++e2) { p[e2] = expf(p[e2] - mx); s += p[e2]; }
  const float inv = 1.f / s;
  #pragma unroll
  for (int e2 = 0; e2 < 8; ++e2) p[e2] *= inv;

  if (lane == 0) {
    int i1 = 0; float v1 = p[0];
    #pragma unroll
    for (int e2 = 1; e2 < 8; ++e2) if (p[e2] > v1) { v1 = p[e2]; i1 = e2; }
    int i2 = 0; float v2 = -1.f;
    #pragma unroll
    for (int e2 = 0; e2 < 8; ++e2) if (e2 != i1 && p[e2] > v2) { v2 = p[e2]; i2 = e2; }
    const float den = v1 + v2 + 1e-6f;
    const int p1 = atomicAdd(&cnt[i1], 1);
    list[i1 * NTOK + p1] = t; pairw[i1 * NTOK + p1] = v1 / den;
    const int p2 = atomicAdd(&cnt[i2], 1);
    list[i2 * NTOK + p2] = t; pairw[i2 * NTOK + p2] = v2 / den;
    #pragma unroll
    for (int e2 = 0; e2 < 8; ++e2) atomicAdd(&sp[e2], p[e2]);
  }
  __syncthreads();
  if (tid < 8) atomicAdd(&sump[tid], sp[tid]);
}

// ---------------- fp32 [R][C] -> bf16 [C][R] transpose ----------------
__global__ __launch_bounds__(256) void conv_transpose(
    const float* __restrict__ in, u16* __restrict__ out, int R, int C) {
  __shared__ float tile[64][65];
  const int e = blockIdx.z;
  const float* pin = in + (size_t)e * R * C;
  u16* pout = out + (size_t)e * R * C;
  const int tx = threadIdx.x & 15;
  const int ty = threadIdx.x >> 4;
  const int c0 = blockIdx.x * 64;
  const int r0 = blockIdx.y * 64;
  #pragma unroll
  for (int i = 0; i < 4; ++i) {
    const int r = ty + i * 16;
    const float4 v = *(const float4*)(pin + (size_t)(r0 + r) * C + c0 + tx * 4);
    tile[r][tx * 4 + 0] = v.x;
    tile[r][tx * 4 + 1] = v.y;
    tile[r][tx * 4 + 2] = v.z;
    tile[r][tx * 4 + 3] = v.w;
  }
  __syncthreads();
  #pragma unroll
  for (int i = 0; i < 4; ++i) {
    const int c = ty + i * 16;
    u16x4 o;
    o[0] = bf16rne(tile[tx * 4 + 0][c]);
    o[1] = bf16rne(tile[tx * 4 + 1][c]);
    o[2] = bf16rne(tile[tx * 4 + 2][c]);
    o[3] = bf16rne(tile[tx * 4 + 3][c]);
    *(u16x4*)(pout + (size_t)(c0 + c) * R + r0 + tx * 4) = o;
  }
}

// ---------------- routing finalize ----------------
__global__ void route_finalize(const int* __restrict__ cnt, const float* __restrict__ sump,
                               int* __restrict__ padc, int* __restrict__ offs,
                               int* __restrict__ list, float* __restrict__ pairw,
                               int* __restrict__ t1e, int* __restrict__ t1r,
                               int* __restrict__ t2e, int* __restrict__ t2r,
                               float* __restrict__ lb_out) {
  __shared__ int s_c[8], s_p[8];
  const int tid = threadIdx.x;
  if (tid == 0) {
    int o = 0; float lb = 0.f;
    for (int e = 0; e < 8; ++e) {
      const int c = cnt[e];
      const int pc = (c + 127) & ~127;
      s_c[e] = c; s_p[e] = pc;
      padc[e] = pc; offs[e] = o; o += pc;
      lb += ((float)c / 8192.f) * (sump[e] / 8192.f);
    }
    lb_out[0] = 0.01f * 8.f * lb;
    int n1 = 0;
    for (int e = 0; e < 8; ++e)
      for (int r = 0; r < s_p[e]; r += 256) { t1e[n1] = e; t1r[n1] = r; ++n1; }
    for (; n1 < 72; ++n1) { t1e[n1] = -1; t1r[n1] = 0; }
    int n2 = 0;
    for (int e = 0; e < 8; ++e)
      for (int r = 0; r < s_p[e]; r += 256) { t2e[n2] = e; t2r[n2] = r; ++n2; }
    for (; n2 < 72; ++n2) { t2e[n2] = -1; t2r[n2] = 0; }
  }
  __syncthreads();
  for (int e = 0; e < 8; ++e)
    for (int pq = s_c[e] + tid; pq < s_p[e]; pq += blockDim.x) {
      list[e * NTOK + pq] = 0; pairw[e * NTOK + pq] = 0.f;
    }
}

// ---------------- GEMM1: 256x256x64, 2-phase/K-tile (4 barriers), reg-double-buffered ----
// P0: read kk1 operands; stage(kk0,t+2); bar; 32 MFMA kk0; bar.
// P1: stage(kk1,t+2); vmcnt(8); bar; read-ahead next kk0; 32 MFMA kk1; bar.
#define G1_NT 16
__global__ __launch_bounds__(512, 2) void gemm1_kernel(
    const u16* __restrict__ xb, const u16* __restrict__ w1t,
    const float* __restrict__ b1, const int* __restrict__ list,
    const int* __restrict__ padc, const int* __restrict__ offs,
    const int* __restrict__ t1e, const int* __restrict__ t1r,
    u16* __restrict__ act) {
  const int tt = blockIdx.y;
  const int e = t1e[tt];
  if (e < 0) return;
  const int row0 = t1r[tt];
  const int j = blockIdx.x;
  const int pc = padc[e];
  const int off_e = offs[e];

  __shared__ u16 lds[65536];  // 128 KiB

  const int tid = threadIdx.x;
  const int lane = tid & 63;
  const int wv = tid >> 6;
  const int wr = wv >> 2, wc = wv & 3;
  const int l15 = lane & 15, l4 = lane >> 4;

  const int rt0 = tid >> 2, rt1 = rt0 + 128;
  const int ce = ((tid & 3) ^ ((rt0 >> 1) & 3)) * 8;
  const int slot0 = row0 + rt0, slot1 = row0 + rt1;
  const int tok0 = (slot0 < pc) ? list[e * NTOK + slot0] : 0;
  const int tok1 = (slot1 < pc) ? list[e * NTOK + slot1] : 0;
  const u16* srcA0 = xb + (size_t)tok0 * DDIM + ce;
  const u16* srcA1 = xb + (size_t)tok1 * DDIM + ce;
  const int gn0 = j * 128 + (rt0 >> 5) * 16 + (rt0 & 15) + ((rt0 >> 4) & 1) * FDIM;
  const int gn1 = j * 128 + (rt1 >> 5) * 16 + (rt1 & 15) + ((rt1 >> 4) & 1) * FDIM;
  const u16* srcB0 = w1t + ((size_t)e * 2 * FDIM + gn0) * DDIM + ce;
  const u16* srcB1 = w1t + ((size_t)e * 2 * FDIM + gn1) * DDIM + ce;

  const int kel = (l4 ^ ((l15 >> 1) & 3)) * 8;
  const int aBase = (wr * 128 + l15) * 32 + kel;
  const int bBase = (wc * 64 + l15) * 32 + kel;

  f32x4 acc[8][4];
  #pragma unroll
  for (int m = 0; m < 8; ++m)
    #pragma unroll
    for (int n = 0; n < 4; ++n) { acc[m][n][0]=0.f; acc[m][n][1]=0.f; acc[m][n][2]=0.f; acc[m][n][3]=0.f; }

  #define STAGE_A(buf, kk, kt) do { \
    u16* _d = &lds[(buf) * 16384 + (kk) * 8192 + wv * 512]; \
    load_lds16(srcA0 + (kt) * 64 + (kk) * 32, _d); \
    load_lds16(srcA1 + (kt) * 64 + (kk) * 32, _d + 4096); \
  } while (0)
  #define STAGE_B(buf, kk, kt) do { \
    u16* _d = &lds[32768 + (buf) * 16384 + (kk) * 8192 + wv * 512]; \
    load_lds16(srcB0 + (kt) * 64 + (kk) * 32, _d); \
    load_lds16(srcB1 + (kt) * 64 + (kk) * 32, _d + 4096); \
  } while (0)

  // prologue: stage tile0 (8) + tile1 (8); land tile0; pre-read kk0; barrier
  STAGE_A(0, 0, 0); STAGE_B(0, 0, 0); STAGE_A(0, 1, 0); STAGE_B(0, 1, 0);
  STAGE_A(1, 0, 1); STAGE_B(1, 0, 1); STAGE_A(1, 1, 1); STAGE_B(1, 1, 1);
  asm volatile("s_waitcnt vmcnt(8)" ::: "memory");
  __builtin_amdgcn_s_barrier();

  bf16x8 aK0[8], aK1[8], bK0[4], bK1[4];
  #pragma unroll
  for (int m = 0; m < 8; ++m) aK0[m] = *(const bf16x8*)&lds[aBase + m * 512];
  #pragma unroll
  for (int n = 0; n < 4; ++n) bK0[n] = *(const bf16x8*)&lds[32768 + bBase + n * 512];
  __builtin_amdgcn_sched_barrier(0);
  __builtin_amdgcn_s_barrier();   // protects tile0-kk0 from t=0 P0 overwrite

  for (int t = 0; t < G1_NT; ++t) {
    const int cur = t & 1;
    const int Ac1 = cur * 16384 + 8192;
    const int Bc1 = 32768 + cur * 16384 + 8192;
    // ---- P0: read kk1 operands; stage (kk0, t+2); 32 MFMA kk0 ----
    {
      #pragma unroll
      for (int m = 0; m < 8; ++m) aK1[m] = *(const bf16x8*)&lds[Ac1 + aBase + m * 512];
      #pragma unroll
      for (int n = 0; n < 4; ++n) bK1[n] = *(const bf16x8*)&lds[Bc1 + bBase + n * 512];
      __builtin_amdgcn_sched_barrier(0);
      if (t + 2 < G1_NT) { STAGE_A(cur, 0, t + 2); STAGE_B(cur, 0, t + 2); }
      __builtin_amdgcn_s_barrier();
      __builtin_amdgcn_s_setprio(1);
      #pragma unroll
      for (int m = 0; m < 8; ++m)
        #pragma unroll
        for (int n = 0; n < 4; ++n)
          acc[m][n] = __builtin_amdgcn_mfma_f32_16x16x32_bf16(aK0[m], bK0[n], acc[m][n], 0, 0, 0);
      __builtin_amdgcn_s_setprio(0);
      __builtin_amdgcn_s_barrier();
    }
    // ---- P1: stage (kk1, t+2); drain; read-ahead next kk0; 32 MFMA kk1 ----
    {
      if (t + 2 < G1_NT) { STAGE_A(cur, 1, t + 2); STAGE_B(cur, 1, t + 2); }
      if (t < G1_NT - 1) {
        if (t == G1_NT - 2) asm volatile("s_waitcnt vmcnt(0)" ::: "memory");
        else                asm volatile("s_waitcnt vmcnt(8)" ::: "memory");
      }
      __builtin_amdgcn_s_barrier();
      if (t + 1 < G1_NT) {
        const int nA = (cur ^ 1) * 16384;
        const int nB = 32768 + (cur ^ 1) * 16384;
        #pragma unroll
        for (int m = 0; m < 8; ++m) aK0[m] = *(const bf16x8*)&lds[nA + aBase + m * 512];
        #pragma unroll
        for (int n = 0; n < 4; ++n) bK0[n] = *(const bf16x8*)&lds[nB + bBase + n * 512];
        __builtin_amdgcn_sched_barrier(0);
      }
      __builtin_amdgcn_s_setprio(1);
      #pragma unroll
      for (int m = 0; m < 8; ++m)
        #pragma unroll
        for (int n = 0; n < 4; ++n)
          acc[m][n] = __builtin_amdgcn_mfma_f32_16x16x32_bf16(aK1[m], bK1[n], acc[m][n], 0, 0, 0);
      __builtin_amdgcn_s_setprio(0);
      __builtin_amdgcn_s_barrier();
    }
  }
  #undef STAGE_A
  #undef STAGE_B

  // ---- epilogue: bias + SwiGLU (fast tanh-gelu), guarded bf16 store ----
  const int rowlim = pc - row0;
  const size_t actrow0 = (size_t)(off_e + row0);
  #pragma unroll
  for (int p2 = 0; p2 < 2; ++p2) {
    const int col = j * 128 + (wc * 2 + p2) * 16 + l15;
    const float ba = b1[e * (2 * FDIM) + col];
    const float bg = b1[e * (2 * FDIM) + FDIM + col];
    #pragma unroll
    for (int m = 0; m < 8; ++m) {
      #pragma unroll
      for (int jr = 0; jr < 4; ++jr) {
        const int row = wr * 128 + m * 16 + l4 * 4 + jr;
        if (row < rowlim) {
          const float a = acc[m][2 * p2][jr] + ba;
          const float g = acc[m][2 * p2 + 1][jr] + bg;
          const float u = 0.7978845608028654f * (g + 0.044715f * g * g * g);
          const float ex = __expf(2.f * u);
          const float th = 1.f - 2.f / (ex + 1.f);
          const float gg = 0.5f * g * (1.f + th);
          act[(actrow0 + row) * FDIM + col] = bf16rne(a * gg);
        }
      }
    }
  }
}

// ---------------- GEMM2: 256x128x64, 2-phase/K-tile, reg-double-buffered; atomic out ----
#define G2_NT 64
__global__ __launch_bounds__(512, 2) void gemm2_kernel(
    const u16* __restrict__ act, const u16* __restrict__ w2t,
    const float* __restrict__ b2, const int* __restrict__ list,
    const float* __restrict__ pairw, const int* __restrict__ padc,
    const int* __restrict__ offs,
    const int* __restrict__ t2e, const int* __restrict__ t2r,
    float* __restrict__ out) {
  const int tt = blockIdx.y;
  const int e = t2e[tt];
  if (e < 0) return;
  const int row0 = t2r[tt];
  const int jt = blockIdx.x;
  const int pc = padc[e];
  const int off_e = offs[e];

  __shared__ u16 lds[49152];  // 96 KiB

  const int tid = threadIdx.x;
  const int lane = tid & 63;
  const int wv = tid >> 6;
  const int wr = wv >> 2, wc = wv & 3;
  const int l15 = lane & 15, l4 = lane >> 4;

  const int rt0 = tid >> 2, rt1 = rt0 + 128;
  const int ce = ((tid & 3) ^ ((rt0 >> 1) & 3)) * 8;
  const u16* srcA0 = act + (size_t)(off_e + row0 + rt0) * FDIM + ce;
  const u16* srcA1 = act + (size_t)(off_e + row0 + rt1) * FDIM + ce;
  const u16* srcB0 = w2t + ((size_t)e * DDIM + jt * 128 + rt0) * FDIM + ce;

  const int kel = (l4 ^ ((l15 >> 1) & 3)) * 8;
  const int aBase = (wr * 128 + l15) * 32 + kel;
  const int bBase = (wc * 32 + l15) * 32 + kel;

  f32x4 acc[8][2];
  #pragma unroll
  for (int m = 0; m < 8; ++m)
    #pragma unroll
    for (int n = 0; n < 2; ++n) { acc[m][n][0]=0.f; acc[m][n][1]=0.f; acc[m][n][2]=0.f; acc[m][n][3]=0.f; }

  #define STAGE2_A(buf, kk, kt) do { \
    u16* _d = &lds[(buf) * 16384 + (kk) * 8192 + wv * 512]; \
    load_lds16(srcA0 + (kt) * 64 + (kk) * 32, _d); \
    load_lds16(srcA1 + (kt) * 64 + (kk) * 32, _d + 4096); \
  } while (0)
  #define STAGE2_B(buf, kk, kt) do { \
    u16* _d = &lds[32768 + (buf) * 8192 + (kk) * 4096 + wv * 512]; \
    load_lds16(srcB0 + (kt) * 64 + (kk) * 32, _d); \
  } while (0)

  // prologue: tile0 (6) + tile1 (6); land tile0; pre-read kk0; barrier
  STAGE2_A(0, 0, 0); STAGE2_B(0, 0, 0); STAGE2_A(0, 1, 0); STAGE2_B(0, 1, 0);
  STAGE2_A(1, 0, 1); STAGE2_B(1, 0, 1); STAGE2_A(1, 1, 1); STAGE2_B(1, 1, 1);
  asm volatile("s_waitcnt vmcnt(6)" ::: "memory");
  __builtin_amdgcn_s_barrier();

  bf16x8 aK0[8], aK1[8], bK0[2], bK1[2];
  #pragma unroll
  for (int m = 0; m < 8; ++m) aK0[m] = *(const bf16x8*)&lds[aBase + m * 512];
  #pragma unroll
  for (int n = 0; n < 2; ++n) bK0[n] = *(const bf16x8*)&lds[32768 + bBase + n * 512];
  __builtin_amdgcn_sched_barrier(0);
  __builtin_amdgcn_s_barrier();

  for (int t = 0; t < G2_NT; ++t) {
    const int cur = t & 1;
    const int Ac1 = cur * 16384 + 8192;
    const int Bc1 = 32768 + cur * 8192 + 4096;
    // ---- P0: read kk1 operands; stage (kk0, t+2); 16 MFMA kk0 ----
    {
      #pragma unroll
      for (int m = 0; m < 8; ++m) aK1[m] = *(const bf16x8*)&lds[Ac1 + aBase + m * 512];
      #pragma unroll
      for (int n = 0; n < 2; ++n) bK1[n] = *(const bf16x8*)&lds[Bc1 + bBase + n * 512];
      __builtin_amdgcn_sched_barrier(0);
      if (t + 2 < G2_NT) { STAGE2_A(cur, 0, t + 2); STAGE2_B(cur, 0, t + 2); }
      __builtin_amdgcn_s_barrier();
      __builtin_amdgcn_s_setprio(1);
      #pragma unroll
      for (int m = 0; m < 8; ++m) {
        acc[m][0] = __builtin_amdgcn_mfma_f32_16x16x32_bf16(aK0[m], bK0[0], acc[m][0], 0, 0, 0);
        acc[m][1] = __builtin_amdgcn_mfma_f32_16x16x32_bf16(aK0[m], bK0[1], acc[m][1], 0, 0, 0);
      }
      __builtin_amdgcn_s_setprio(0);
      __builtin_amdgcn_s_barrier();
    }
    // ---- P1: stage (kk1, t+2); drain; read-ahead next kk0; 16 MFMA kk1 ----
    {
      if (t + 2 < G2_NT) { STAGE2_A(cur, 1, t + 2); STAGE2_B(cur, 1, t + 2); }
      if (t < G2_NT - 1) {
        if (t == G2_NT - 2) asm volatile("s_waitcnt vmcnt(0)" ::: "memory");
        else                asm volatile("s_waitcnt vmcnt(6)" ::: "memory");
      }
      __builtin_amdgcn_s_barrier();
      if (t + 1 < G2_NT) {
        const int nA = (cur ^ 1) * 16384;
        const int nB = 32768 + (cur ^ 1) * 8192;
        #pragma unroll
        for (int m = 0; m < 8; ++m) aK0[m] = *(const bf16x8*)&lds[nA + aBase + m * 512];
        #pragma unroll
        for (int n = 0; n < 2; ++n) bK0[n] = *(const bf16x8*)&lds[nB + bBase + n * 512];
        __builtin_amdgcn_sched_barrier(0);
      }
      __builtin_amdgcn_s_setprio(1);
      #pragma unroll
      for (int m = 0; m < 8; ++m) {
        acc[m][0] = __builtin_amdgcn_mfma_f32_16x16x32_bf16(aK1[m], bK1[0], acc[m][0], 0, 0, 0);
        acc[m][1] = __builtin_amdgcn_mfma_f32_16x16x32_bf16(aK1[m], bK1[1], acc[m][1], 0, 0, 0);
      }
      __builtin_amdgcn_s_setprio(0);
      __builtin_amdgcn_s_barrier();
    }
  }
  #undef STAGE2_A
  #undef STAGE2_B

  // ---- epilogue: weighted atomic accumulation into out ----
  const int rowlim = pc - row0;
  #pragma unroll
  for (int m = 0; m < 8; ++m) {
    #pragma unroll
    for (int jr = 0; jr < 4; ++jr) {
      const int row = wr * 128 + m * 16 + l4 * 4 + jr;
      if (row < rowlim) {
        const int pos = row0 + row;
        const int tok = list[e * NTOK + pos];
        const float pw = pairw[e * NTOK + pos];
        if (pw != 0.f) {
          #pragma unroll
          for (int n = 0; n < 2; ++n) {
            const int col = jt * 128 + wc * 32 + n * 16 + l15;
            const float v = (acc[m][n][jr] + b2[e * DDIM + col]) * pw;
            atomicAdd(&out[(size_t)tok * DDIM + col], v);
          }
        }
      }
    }
  }
}

extern "C" void kernel_launch(void* const* d_in, const int* in_sizes, int n_in,
                              void* d_out, int out_size, void* d_ws, size_t ws_size,
                              hipStream_t stream) {
  const float* x   = (const float*)d_in[0];
  const float* gw  = (const float*)d_in[1];
  const float* gb  = (const float*)d_in[2];
  const float* f1w = (const float*)d_in[3];
  const float* f1b = (const float*)d_in[4];
  const float* f2w = (const float*)d_in[5];
  const float* f2b = (const float*)d_in[6];
  float* out = (float*)d_out;
  char* ws = (char*)d_ws;

  u16*   xb    = (u16*)(ws + WS_XB);
  u16*   w1t   = (u16*)(ws + WS_W1T);
  u16*   w2t   = (u16*)(ws + WS_W2T);
  u16*   act   = (u16*)(ws + WS_ACT);
  int*   list  = (int*)(ws + WS_LIST);
  float* pairw = (float*)(ws + WS_PAIRW);
  int*   cnt   = (int*)(ws + WS_CNT);
  float* sump  = (float*)(ws + WS_SUMP);
  int*   padc  = (int*)(ws + WS_PAD);
  int*   offs  = (int*)(ws + WS_OFF);
  int*   t1e   = (int*)(ws + WS_T1E);
  int*   t1r   = (int*)(ws + WS_T1R);
  int*   t2e   = (int*)(ws + WS_T2E);
  int*   t2r   = (int*)(ws + WS_T2R);

  (void)hipMemsetAsync(d_out, 0, (size_t)out_size * sizeof(float), stream);
  (void)hipMemsetAsync(ws + WS_CNT, 0, 64, stream);  // cnt + sump

  gate_kernel<<<NTOK / 4, 256, 0, stream>>>(x, gw, gb, xb, cnt, sump, list, pairw);
  conv_transpose<<<dim3(8192 / 64, 1024 / 64, 8), 256, 0, stream>>>(f1w, w1t, 1024, 8192);
  conv_transpose<<<dim3(1024 / 64, 4096 / 64, 8), 256, 0, stream>>>(f2w, w2t, 4096, 1024);
  route_finalize<<<1, 256, 0, stream>>>(cnt, sump, padc, offs, list, pairw,
                                        t1e, t1r, t2e, t2r, out + 8388608);
  gemm1_kernel<<<dim3(32, 72), 512, 0, stream>>>(xb, w1t, f1b, list, padc, offs, t1e, t1r, act);
  gemm2_kernel<<<dim3(8, 72), 512, 0, stream>>>(act, w2t, f2b, list, pairw, padc, offs, t2e, t2r, out);
}

// Round 8
// 1093.587 us; speedup vs baseline: 1.0601x; 1.0601x over previous
//
#include <hip/hip_runtime.h>
#include <hip/hip_bf16.h>
#include <stdint.h>

typedef __attribute__((ext_vector_type(4))) float f32x4;
typedef __attribute__((ext_vector_type(8))) __bf16 bf16x8;
typedef __attribute__((ext_vector_type(4))) unsigned short u16x4;
typedef unsigned short u16;

#define NTOK 8192
#define DDIM 1024
#define FDIM 4096
#define NEXP 8

// ---- workspace layout (bytes) ----
#define WS_XB    0ull
#define WS_W1T   (16777216ull)
#define WS_W2T   (WS_W1T + 134217728ull)
#define WS_ACT   (WS_W2T + 67108864ull)
#define WS_LIST  (WS_ACT + 142606336ull)
#define WS_PAIRW (WS_LIST + 262144ull)
#define WS_CNT   (WS_PAIRW + 262144ull)
#define WS_SUMP  (WS_CNT + 32ull)
#define WS_PAD   (WS_SUMP + 32ull)
#define WS_OFF   (WS_PAD + 32ull)
#define WS_T1E   (WS_OFF + 32ull)
#define WS_T1R   (WS_T1E + 512ull)
#define WS_T2E   (WS_T1R + 512ull)
#define WS_T2R   (WS_T2E + 1024ull)

static __device__ __forceinline__ u16 bf16rne(float f) {
  union { float f; uint32_t u; } c; c.f = f;
  return (u16)((c.u + 0x7FFFu + ((c.u >> 16) & 1u)) >> 16);
}

static __device__ __forceinline__ void load_lds16(const void* g, void* l) {
  __builtin_amdgcn_global_load_lds((const __attribute__((address_space(1))) void*)g,
                                   (__attribute__((address_space(3))) void*)l, 16, 0, 0);
}

// ---------------- gating + routing + x->bf16 ----------------
__global__ __launch_bounds__(256) void gate_kernel(
    const float* __restrict__ x, const float* __restrict__ gw,
    const float* __restrict__ gb, u16* __restrict__ xb,
    int* __restrict__ cnt, float* __restrict__ sump,
    int* __restrict__ list, float* __restrict__ pairw) {
  const int tid = threadIdx.x;
  const int lane = tid & 63;
  const int wv = tid >> 6;
  const int t = blockIdx.x * 4 + wv;

  __shared__ float sp[8];
  if (tid < 8) sp[tid] = 0.f;
  __syncthreads();

  float acc[8] = {0.f,0.f,0.f,0.f,0.f,0.f,0.f,0.f};
  const float4* x4 = (const float4*)x + (size_t)t * 256;
  u16x4* xb4 = (u16x4*)xb + (size_t)t * 256;
  #pragma unroll
  for (int it = 0; it < 4; ++it) {
    const float4 xv = x4[it * 64 + lane];
    u16x4 bv;
    bv[0] = bf16rne(xv.x); bv[1] = bf16rne(xv.y);
    bv[2] = bf16rne(xv.z); bv[3] = bf16rne(xv.w);
    xb4[it * 64 + lane] = bv;
    const int d0 = (it * 64 + lane) * 4;
    #pragma unroll
    for (int j = 0; j < 4; ++j) {
      const float xs = (j == 0) ? xv.x : ((j == 1) ? xv.y : ((j == 2) ? xv.z : xv.w));
      const float* g = gw + (size_t)(d0 + j) * 8;
      #pragma unroll
      for (int e2 = 0; e2 < 8; ++e2) acc[e2] += xs * g[e2];
    }
  }
  #pragma unroll
  for (int e2 = 0; e2 < 8; ++e2) {
    float v = acc[e2];
    v += __shfl_xor(v, 1);  v += __shfl_xor(v, 2);  v += __shfl_xor(v, 4);
    v += __shfl_xor(v, 8);  v += __shfl_xor(v, 16); v += __shfl_xor(v, 32);
    acc[e2] = v;
  }
  float p[8]; float mx = -1e30f;
  #pragma unroll
  for (int e2 = 0; e2 < 8; ++e2) { p[e2] = acc[e2] + gb[e2]; mx = fmaxf(mx, p[e2]); }
  float s = 0.f;
  #pragma unroll
  for (int e2 = 0; e2 < 8; ++e2) { p[e2] = expf(p[e2] - mx); s += p[e2]; }
  const float inv = 1.f / s;
  #pragma unroll
  for (int e2 = 0; e2 < 8; ++e2) p[e2] *= inv;

  if (lane == 0) {
    int i1 = 0; float v1 = p[0];
    #pragma unroll
    for (int e2 = 1; e2 < 8; ++e2) if (p[e2] > v1) { v1 = p[e2]; i1 = e2; }
    int i2 = 0; float v2 = -1.f;
    #pragma unroll
    for (int e2 = 0; e2 < 8; ++e2) if (e2 != i1 && p[e2] > v2) { v2 = p[e2]; i2 = e2; }
    const float den = v1 + v2 + 1e-6f;
    const int p1 = atomicAdd(&cnt[i1], 1);
    list[i1 * NTOK + p1] = t; pairw[i1 * NTOK + p1] = v1 / den;
    const int p2 = atomicAdd(&cnt[i2], 1);
    list[i2 * NTOK + p2] = t; pairw[i2 * NTOK + p2] = v2 / den;
    #pragma unroll
    for (int e2 = 0; e2 < 8; ++e2) atomicAdd(&sp[e2], p[e2]);
  }
  __syncthreads();
  if (tid < 8) atomicAdd(&sump[tid], sp[tid]);
}

// ---------------- fp32 [R][C] -> bf16 [C][R] transpose ----------------
__global__ __launch_bounds__(256) void conv_transpose(
    const float* __restrict__ in, u16* __restrict__ out, int R, int C) {
  __shared__ float tile[64][65];
  const int e = blockIdx.z;
  const float* pin = in + (size_t)e * R * C;
  u16* pout = out + (size_t)e * R * C;
  const int tx = threadIdx.x & 15;
  const int ty = threadIdx.x >> 4;
  const int c0 = blockIdx.x * 64;
  const int r0 = blockIdx.y * 64;
  #pragma unroll
  for (int i = 0; i < 4; ++i) {
    const int r = ty + i * 16;
    const float4 v = *(const float4*)(pin + (size_t)(r0 + r) * C + c0 + tx * 4);
    tile[r][tx * 4 + 0] = v.x;
    tile[r][tx * 4 + 1] = v.y;
    tile[r][tx * 4 + 2] = v.z;
    tile[r][tx * 4 + 3] = v.w;
  }
  __syncthreads();
  #pragma unroll
  for (int i = 0; i < 4; ++i) {
    const int c = ty + i * 16;
    u16x4 o;
    o[0] = bf16rne(tile[tx * 4 + 0][c]);
    o[1] = bf16rne(tile[tx * 4 + 1][c]);
    o[2] = bf16rne(tile[tx * 4 + 2][c]);
    o[3] = bf16rne(tile[tx * 4 + 3][c]);
    *(u16x4*)(pout + (size_t)(c0 + c) * R + r0 + tx * 4) = o;
  }
}

// ---------------- routing finalize ----------------
__global__ void route_finalize(const int* __restrict__ cnt, const float* __restrict__ sump,
                               int* __restrict__ padc, int* __restrict__ offs,
                               int* __restrict__ list, float* __restrict__ pairw,
                               int* __restrict__ t1e, int* __restrict__ t1r,
                               int* __restrict__ t2e, int* __restrict__ t2r,
                               float* __restrict__ lb_out) {
  __shared__ int s_c[8], s_p[8];
  const int tid = threadIdx.x;
  if (tid == 0) {
    int o = 0; float lb = 0.f;
    for (int e = 0; e < 8; ++e) {
      const int c = cnt[e];
      const int pc = (c + 127) & ~127;
      s_c[e] = c; s_p[e] = pc;
      padc[e] = pc; offs[e] = o; o += pc;
      lb += ((float)c / 8192.f) * (sump[e] / 8192.f);
    }
    lb_out[0] = 0.01f * 8.f * lb;
    int n1 = 0;
    for (int e = 0; e < 8; ++e)
      for (int r = 0; r < s_p[e]; r += 256) { t1e[n1] = e; t1r[n1] = r; ++n1; }
    for (; n1 < 72; ++n1) { t1e[n1] = -1; t1r[n1] = 0; }
    int n2 = 0;
    for (int e = 0; e < 8; ++e)
      for (int r = 0; r < s_p[e]; r += 256) { t2e[n2] = e; t2r[n2] = r; ++n2; }
    for (; n2 < 72; ++n2) { t2e[n2] = -1; t2r[n2] = 0; }
  }
  __syncthreads();
  for (int e = 0; e < 8; ++e)
    for (int pq = s_c[e] + tid; pq < s_p[e]; pq += blockDim.x) {
      list[e * NTOK + pq] = 0; pairw[e * NTOK + pq] = 0.f;
    }
}

// ---------------- GEMM1: 256x256x64 8-phase counted-vmcnt, fused SwiGLU ----------------
// R8: NO sched_barrier in the K-loop (m141 lesson) — compiler emits fine-grained
// lgkmcnt so early MFMAs overlap late ds_reads. STAGE issued at phase top.
#define G1_NT 16
__global__ __launch_bounds__(512, 2) void gemm1_kernel(
    const u16* __restrict__ xb, const u16* __restrict__ w1t,
    const float* __restrict__ b1, const int* __restrict__ list,
    const int* __restrict__ padc, const int* __restrict__ offs,
    const int* __restrict__ t1e, const int* __restrict__ t1r,
    u16* __restrict__ act) {
  const int tt = blockIdx.y;
  const int e = t1e[tt];
  if (e < 0) return;
  const int row0 = t1r[tt];
  const int j = blockIdx.x;
  const int pc = padc[e];
  const int off_e = offs[e];

  __shared__ u16 lds[65536];  // 128 KiB

  const int tid = threadIdx.x;
  const int lane = tid & 63;
  const int wv = tid >> 6;
  const int wr = wv >> 2, wc = wv & 3;
  const int l15 = lane & 15, l4 = lane >> 4;

  const int rt0 = tid >> 2, rt1 = rt0 + 128;
  const int ce = ((tid & 3) ^ ((rt0 >> 1) & 3)) * 8;
  const int slot0 = row0 + rt0, slot1 = row0 + rt1;
  const int tok0 = (slot0 < pc) ? list[e * NTOK + slot0] : 0;
  const int tok1 = (slot1 < pc) ? list[e * NTOK + slot1] : 0;
  const u16* srcA0 = xb + (size_t)tok0 * DDIM + ce;
  const u16* srcA1 = xb + (size_t)tok1 * DDIM + ce;
  const int gn0 = j * 128 + (rt0 >> 5) * 16 + (rt0 & 15) + ((rt0 >> 4) & 1) * FDIM;
  const int gn1 = j * 128 + (rt1 >> 5) * 16 + (rt1 & 15) + ((rt1 >> 4) & 1) * FDIM;
  const u16* srcB0 = w1t + ((size_t)e * 2 * FDIM + gn0) * DDIM + ce;
  const u16* srcB1 = w1t + ((size_t)e * 2 * FDIM + gn1) * DDIM + ce;

  const int kel = (l4 ^ ((l15 >> 1) & 3)) * 8;
  const int aBase = (wr * 128 + l15) * 32 + kel;
  const int bBase = (wc * 64 + l15) * 32 + kel;

  f32x4 acc[8][4];
  #pragma unroll
  for (int m = 0; m < 8; ++m)
    #pragma unroll
    for (int n = 0; n < 4; ++n) { acc[m][n][0]=0.f; acc[m][n][1]=0.f; acc[m][n][2]=0.f; acc[m][n][3]=0.f; }

  #define STAGE_A(buf, kk, kt) do { \
    u16* _d = &lds[(buf) * 16384 + (kk) * 8192 + wv * 512]; \
    load_lds16(srcA0 + (kt) * 64 + (kk) * 32, _d); \
    load_lds16(srcA1 + (kt) * 64 + (kk) * 32, _d + 4096); \
  } while (0)
  #define STAGE_B(buf, kk, kt) do { \
    u16* _d = &lds[32768 + (buf) * 16384 + (kk) * 8192 + wv * 512]; \
    load_lds16(srcB0 + (kt) * 64 + (kk) * 32, _d); \
    load_lds16(srcB1 + (kt) * 64 + (kk) * 32, _d + 4096); \
  } while (0)

  // prologue: stage tile0 fully + 3 halves of tile1; land tile0
  STAGE_A(0, 0, 0); STAGE_B(0, 0, 0); STAGE_A(0, 1, 0); STAGE_B(0, 1, 0);
  STAGE_A(1, 0, 1); STAGE_B(1, 0, 1); STAGE_A(1, 1, 1);
  asm volatile("s_waitcnt vmcnt(6)" ::: "memory");
  __builtin_amdgcn_s_barrier();

  bf16x8 aF[8];
  for (int t = 0; t < G1_NT; ++t) {
    const int cur = t & 1;
    const int Ac0 = cur * 16384, Ac1 = Ac0 + 8192;
    const int Bc0 = 32768 + cur * 16384, Bc1 = Bc0 + 8192;
    // ---- phase 0: stage; read A kk0 (8) + B kk0 n0,n1; MFMA ----
    {
      if (t + 1 < G1_NT) STAGE_B(cur ^ 1, 1, t + 1);
      #pragma unroll
      for (int m = 0; m < 8; ++m) aF[m] = *(const bf16x8*)&lds[Ac0 + aBase + m * 512];
      bf16x8 b0 = *(const bf16x8*)&lds[Bc0 + bBase + 0 * 512];
      bf16x8 b1f = *(const bf16x8*)&lds[Bc0 + bBase + 1 * 512];
      __builtin_amdgcn_s_barrier();
      __builtin_amdgcn_s_setprio(1);
      #pragma unroll
      for (int m = 0; m < 8; ++m) {
        acc[m][0] = __builtin_amdgcn_mfma_f32_16x16x32_bf16(aF[m], b0, acc[m][0], 0, 0, 0);
        acc[m][1] = __builtin_amdgcn_mfma_f32_16x16x32_bf16(aF[m], b1f, acc[m][1], 0, 0, 0);
      }
      __builtin_amdgcn_s_setprio(0);
      __builtin_amdgcn_s_barrier();
    }
    // ---- phase 1: stage; read B kk0 n2,n3; MFMA ----
    {
      if (t + 2 < G1_NT) STAGE_A(cur, 0, t + 2);
      bf16x8 b2 = *(const bf16x8*)&lds[Bc0 + bBase + 2 * 512];
      bf16x8 b3 = *(const bf16x8*)&lds[Bc0 + bBase + 3 * 512];
      __builtin_amdgcn_s_barrier();
      __builtin_amdgcn_s_setprio(1);
      #pragma unroll
      for (int m = 0; m < 8; ++m) {
        acc[m][2] = __builtin_amdgcn_mfma_f32_16x16x32_bf16(aF[m], b2, acc[m][2], 0, 0, 0);
        acc[m][3] = __builtin_amdgcn_mfma_f32_16x16x32_bf16(aF[m], b3, acc[m][3], 0, 0, 0);
      }
      __builtin_amdgcn_s_setprio(0);
      __builtin_amdgcn_s_barrier();
    }
    // ---- phase 2: stage; read A kk1 (8) + B kk1 n0,n1; MFMA ----
    {
      if (t + 2 < G1_NT) STAGE_B(cur, 0, t + 2);
      #pragma unroll
      for (int m = 0; m < 8; ++m) aF[m] = *(const bf16x8*)&lds[Ac1 + aBase + m * 512];
      bf16x8 b0 = *(const bf16x8*)&lds[Bc1 + bBase + 0 * 512];
      bf16x8 b1f = *(const bf16x8*)&lds[Bc1 + bBase + 1 * 512];
      __builtin_amdgcn_s_barrier();
      __builtin_amdgcn_s_setprio(1);
      #pragma unroll
      for (int m = 0; m < 8; ++m) {
        acc[m][0] = __builtin_amdgcn_mfma_f32_16x16x32_bf16(aF[m], b0, acc[m][0], 0, 0, 0);
        acc[m][1] = __builtin_amdgcn_mfma_f32_16x16x32_bf16(aF[m], b1f, acc[m][1], 0, 0, 0);
      }
      __builtin_amdgcn_s_setprio(0);
      __builtin_amdgcn_s_barrier();
    }
    // ---- phase 3: stage; read B kk1 n2,n3; MFMA; vmcnt at tile boundary ----
    {
      if (t + 2 < G1_NT) STAGE_A(cur, 1, t + 2);
      bf16x8 b2 = *(const bf16x8*)&lds[Bc1 + bBase + 2 * 512];
      bf16x8 b3 = *(const bf16x8*)&lds[Bc1 + bBase + 3 * 512];
      __builtin_amdgcn_s_barrier();
      __builtin_amdgcn_s_setprio(1);
      #pragma unroll
      for (int m = 0; m < 8; ++m) {
        acc[m][2] = __builtin_amdgcn_mfma_f32_16x16x32_bf16(aF[m], b2, acc[m][2], 0, 0, 0);
        acc[m][3] = __builtin_amdgcn_mfma_f32_16x16x32_bf16(aF[m], b3, acc[m][3], 0, 0, 0);
      }
      __builtin_amdgcn_s_setprio(0);
      if (t < G1_NT - 1) {
        if (t == G1_NT - 2) asm volatile("s_waitcnt vmcnt(0)" ::: "memory");
        else                asm volatile("s_waitcnt vmcnt(6)" ::: "memory");
      }
      __builtin_amdgcn_s_barrier();
    }
  }
  #undef STAGE_A
  #undef STAGE_B

  // ---- epilogue: bias + SwiGLU (fast tanh-gelu), guarded bf16 store ----
  const int rowlim = pc - row0;
  const size_t actrow0 = (size_t)(off_e + row0);
  #pragma unroll
  for (int p2 = 0; p2 < 2; ++p2) {
    const int col = j * 128 + (wc * 2 + p2) * 16 + l15;
    const float ba = b1[e * (2 * FDIM) + col];
    const float bg = b1[e * (2 * FDIM) + FDIM + col];
    #pragma unroll
    for (int m = 0; m < 8; ++m) {
      #pragma unroll
      for (int jr = 0; jr < 4; ++jr) {
        const int row = wr * 128 + m * 16 + l4 * 4 + jr;
        if (row < rowlim) {
          const float a = acc[m][2 * p2][jr] + ba;
          const float g = acc[m][2 * p2 + 1][jr] + bg;
          const float u = 0.7978845608028654f * (g + 0.044715f * g * g * g);
          const float ex = __expf(2.f * u);
          const float th = 1.f - 2.f / (ex + 1.f);
          const float gg = 0.5f * g * (1.f + th);
          act[(actrow0 + row) * FDIM + col] = bf16rne(a * gg);
        }
      }
    }
  }
}

// ---------------- GEMM2: 256x128x64 8-phase counted-vmcnt, weighted atomic out ----------------
// Grid: (jt=8 FAST, tt=72). No sched_barrier in loop; STAGE at phase top.
#define G2_NT 64
__global__ __launch_bounds__(512, 2) void gemm2_kernel(
    const u16* __restrict__ act, const u16* __restrict__ w2t,
    const float* __restrict__ b2, const int* __restrict__ list,
    const float* __restrict__ pairw, const int* __restrict__ padc,
    const int* __restrict__ offs,
    const int* __restrict__ t2e, const int* __restrict__ t2r,
    float* __restrict__ out) {
  const int tt = blockIdx.y;
  const int e = t2e[tt];
  if (e < 0) return;
  const int row0 = t2r[tt];
  const int jt = blockIdx.x;
  const int pc = padc[e];
  const int off_e = offs[e];

  __shared__ u16 lds[49152];  // 96 KiB

  const int tid = threadIdx.x;
  const int lane = tid & 63;
  const int wv = tid >> 6;
  const int wr = wv >> 2, wc = wv & 3;
  const int l15 = lane & 15, l4 = lane >> 4;

  const int rt0 = tid >> 2, rt1 = rt0 + 128;
  const int ce = ((tid & 3) ^ ((rt0 >> 1) & 3)) * 8;
  const u16* srcA0 = act + (size_t)(off_e + row0 + rt0) * FDIM + ce;
  const u16* srcA1 = act + (size_t)(off_e + row0 + rt1) * FDIM + ce;
  const u16* srcB0 = w2t + ((size_t)e * DDIM + jt * 128 + rt0) * FDIM + ce;

  const int kel = (l4 ^ ((l15 >> 1) & 3)) * 8;
  const int aBase = (wr * 128 + l15) * 32 + kel;
  const int bBase = (wc * 32 + l15) * 32 + kel;

  f32x4 acc[8][2];
  #pragma unroll
  for (int m = 0; m < 8; ++m)
    #pragma unroll
    for (int n = 0; n < 2; ++n) { acc[m][n][0]=0.f; acc[m][n][1]=0.f; acc[m][n][2]=0.f; acc[m][n][3]=0.f; }

  #define STAGE2_A(buf, kk, kt) do { \
    u16* _d = &lds[(buf) * 16384 + (kk) * 8192 + wv * 512]; \
    load_lds16(srcA0 + (kt) * 64 + (kk) * 32, _d); \
    load_lds16(srcA1 + (kt) * 64 + (kk) * 32, _d + 4096); \
  } while (0)
  #define STAGE2_B(buf, kk, kt) do { \
    u16* _d = &lds[32768 + (buf) * 8192 + (kk) * 4096 + wv * 512]; \
    load_lds16(srcB0 + (kt) * 64 + (kk) * 32, _d); \
  } while (0)

  // prologue: tile0 full (6) + tile1 {B kk0, A kk0, B kk1} (4)
  STAGE2_B(0, 0, 0); STAGE2_A(0, 0, 0); STAGE2_B(0, 1, 0); STAGE2_A(0, 1, 0);
  STAGE2_B(1, 0, 1); STAGE2_A(1, 0, 1); STAGE2_B(1, 1, 1);
  asm volatile("s_waitcnt vmcnt(4)" ::: "memory");
  __builtin_amdgcn_s_barrier();

  bf16x8 aF0[4], aF1[4];
  for (int t = 0; t < G2_NT; ++t) {
    const int cur = t & 1;
    const int Ac0 = cur * 16384, Ac1 = Ac0 + 8192;
    const int Bc0 = 32768 + cur * 8192, Bc1 = Bc0 + 4096;
    // ---- phase 0: stage next A kk1; read A kk0 m0-3 + B kk0; 8 MFMA ----
    bf16x8 b0, b1f;
    {
      if (t + 1 < G2_NT) STAGE2_A(cur ^ 1, 1, t + 1);
      #pragma unroll
      for (int m = 0; m < 4; ++m) aF0[m] = *(const bf16x8*)&lds[Ac0 + aBase + m * 512];
      b0  = *(const bf16x8*)&lds[Bc0 + bBase + 0 * 512];
      b1f = *(const bf16x8*)&lds[Bc0 + bBase + 1 * 512];
      __builtin_amdgcn_s_barrier();
      __builtin_amdgcn_s_setprio(1);
      #pragma unroll
      for (int m = 0; m < 4; ++m) {
        acc[m][0] = __builtin_amdgcn_mfma_f32_16x16x32_bf16(aF0[m], b0, acc[m][0], 0, 0, 0);
        acc[m][1] = __builtin_amdgcn_mfma_f32_16x16x32_bf16(aF0[m], b1f, acc[m][1], 0, 0, 0);
      }
      __builtin_amdgcn_s_setprio(0);
      __builtin_amdgcn_s_barrier();
    }
    // ---- phase 1: stage t+2 B kk0; read A kk0 m4-7; 8 MFMA ----
    {
      if (t + 2 < G2_NT) STAGE2_B(cur, 0, t + 2);
      #pragma unroll
      for (int m = 0; m < 4; ++m) aF1[m] = *(const bf16x8*)&lds[Ac0 + aBase + (m + 4) * 512];
      __builtin_amdgcn_s_barrier();
      __builtin_amdgcn_s_setprio(1);
      #pragma unroll
      for (int m = 0; m < 4; ++m) {
        acc[m + 4][0] = __builtin_amdgcn_mfma_f32_16x16x32_bf16(aF1[m], b0, acc[m + 4][0], 0, 0, 0);
        acc[m + 4][1] = __builtin_amdgcn_mfma_f32_16x16x32_bf16(aF1[m], b1f, acc[m + 4][1], 0, 0, 0);
      }
      __builtin_amdgcn_s_setprio(0);
      __builtin_amdgcn_s_barrier();
    }
    // ---- phase 2: stage t+2 A kk0; read A kk1 m0-3 + B kk1; 8 MFMA ----
    {
      if (t + 2 < G2_NT) STAGE2_A(cur, 0, t + 2);
      #pragma unroll
      for (int m = 0; m < 4; ++m) aF0[m] = *(const bf16x8*)&lds[Ac1 + aBase + m * 512];
      b0  = *(const bf16x8*)&lds[Bc1 + bBase + 0 * 512];
      b1f = *(const bf16x8*)&lds[Bc1 + bBase + 1 * 512];
      __builtin_amdgcn_s_barrier();
      __builtin_amdgcn_s_setprio(1);
      #pragma unroll
      for (int m = 0; m < 4; ++m) {
        acc[m][0] = __builtin_amdgcn_mfma_f32_16x16x32_bf16(aF0[m], b0, acc[m][0], 0, 0, 0);
        acc[m][1] = __builtin_amdgcn_mfma_f32_16x16x32_bf16(aF0[m], b1f, acc[m][1], 0, 0, 0);
      }
      __builtin_amdgcn_s_setprio(0);
      __builtin_amdgcn_s_barrier();
    }
    // ---- phase 3: stage t+2 B kk1; read A kk1 m4-7; 8 MFMA; drain ----
    {
      if (t + 2 < G2_NT) STAGE2_B(cur, 1, t + 2);
      #pragma unroll
      for (int m = 0; m < 4; ++m) aF1[m] = *(const bf16x8*)&lds[Ac1 + aBase + (m + 4) * 512];
      __builtin_amdgcn_s_barrier();
      __builtin_amdgcn_s_setprio(1);
      #pragma unroll
      for (int m = 0; m < 4; ++m) {
        acc[m + 4][0] = __builtin_amdgcn_mfma_f32_16x16x32_bf16(aF1[m], b0, acc[m + 4][0], 0, 0, 0);
        acc[m + 4][1] = __builtin_amdgcn_mfma_f32_16x16x32_bf16(aF1[m], b1f, acc[m + 4][1], 0, 0, 0);
      }
      __builtin_amdgcn_s_setprio(0);
      if (t < G2_NT - 1) {
        if (t == G2_NT - 2) asm volatile("s_waitcnt vmcnt(0)" ::: "memory");
        else                asm volatile("s_waitcnt vmcnt(4)" ::: "memory");
      }
      __builtin_amdgcn_s_barrier();
    }
  }
  #undef STAGE2_A
  #undef STAGE2_B

  // ---- epilogue: weighted atomic accumulation into out ----
  const int rowlim = pc - row0;
  #pragma unroll
  for (int m = 0; m < 8; ++m) {
    #pragma unroll
    for (int jr = 0; jr < 4; ++jr) {
      const int row = wr * 128 + m * 16 + l4 * 4 + jr;
      if (row < rowlim) {
        const int pos = row0 + row;
        const int tok = list[e * NTOK + pos];
        const float pw = pairw[e * NTOK + pos];
        if (pw != 0.f) {
          #pragma unroll
          for (int n = 0; n < 2; ++n) {
            const int col = jt * 128 + wc * 32 + n * 16 + l15;
            const float v = (acc[m][n][jr] + b2[e * DDIM + col]) * pw;
            atomicAdd(&out[(size_t)tok * DDIM + col], v);
          }
        }
      }
    }
  }
}

extern "C" void kernel_launch(void* const* d_in, const int* in_sizes, int n_in,
                              void* d_out, int out_size, void* d_ws, size_t ws_size,
                              hipStream_t stream) {
  const float* x   = (const float*)d_in[0];
  const float* gw  = (const float*)d_in[1];
  const float* gb  = (const float*)d_in[2];
  const float* f1w = (const float*)d_in[3];
  const float* f1b = (const float*)d_in[4];
  const float* f2w = (const float*)d_in[5];
  const float* f2b = (const float*)d_in[6];
  float* out = (float*)d_out;
  char* ws = (char*)d_ws;

  u16*   xb    = (u16*)(ws + WS_XB);
  u16*   w1t   = (u16*)(ws + WS_W1T);
  u16*   w2t   = (u16*)(ws + WS_W2T);
  u16*   act   = (u16*)(ws + WS_ACT);
  int*   list  = (int*)(ws + WS_LIST);
  float* pairw = (float*)(ws + WS_PAIRW);
  int*   cnt   = (int*)(ws + WS_CNT);
  float* sump  = (float*)(ws + WS_SUMP);
  int*   padc  = (int*)(ws + WS_PAD);
  int*   offs  = (int*)(ws + WS_OFF);
  int*   t1e   = (int*)(ws + WS_T1E);
  int*   t1r   = (int*)(ws + WS_T1R);
  int*   t2e   = (int*)(ws + WS_T2E);
  int*   t2r   = (int*)(ws + WS_T2R);

  (void)hipMemsetAsync(d_out, 0, (size_t)out_size * sizeof(float), stream);
  (void)hipMemsetAsync(ws + WS_CNT, 0, 64, stream);  // cnt + sump

  gate_kernel<<<NTOK / 4, 256, 0, stream>>>(x, gw, gb, xb, cnt, sump, list, pairw);
  conv_transpose<<<dim3(8192 / 64, 1024 / 64, 8), 256, 0, stream>>>(f1w, w1t, 1024, 8192);
  conv_transpose<<<dim3(1024 / 64, 4096 / 64, 8), 256, 0, stream>>>(f2w, w2t, 4096, 1024);
  route_finalize<<<1, 256, 0, stream>>>(cnt, sump, padc, offs, list, pairw,
                                        t1e, t1r, t2e, t2r, out + 8388608);
  gemm1_kernel<<<dim3(32, 72), 512, 0, stream>>>(xb, w1t, f1b, list, padc, offs, t1e, t1r, act);
  gemm2_kernel<<<dim3(8, 72), 512, 0, stream>>>(act, w2t, f2b, list, pairw, padc, offs, t2e, t2r, out);
}

// Round 9
// 1011.687 us; speedup vs baseline: 1.1460x; 1.0810x over previous
//
#include <hip/hip_runtime.h>
#include <hip/hip_bf16.h>
#include <stdint.h>

typedef __attribute__((ext_vector_type(4))) float f32x4;
typedef __attribute__((ext_vector_type(8))) __bf16 bf16x8;
typedef __attribute__((ext_vector_type(4))) unsigned short u16x4;
typedef unsigned short u16;

#define NTOK 8192
#define DDIM 1024
#define FDIM 4096
#define NEXP 8
#define NT1 144

// ---- workspace layout (bytes) ----
#define WS_XB    0ull
#define WS_W1T   (16777216ull)
#define WS_W2T   (WS_W1T + 134217728ull)
#define WS_ACT   (WS_W2T + 67108864ull)
#define WS_LIST  (WS_ACT + 142606336ull)
#define WS_PAIRW (WS_LIST + 262144ull)
#define WS_CNT   (WS_PAIRW + 262144ull)
#define WS_SUMP  (WS_CNT + 32ull)
#define WS_PAD   (WS_SUMP + 32ull)
#define WS_OFF   (WS_PAD + 32ull)
#define WS_T1E   (WS_OFF + 32ull)        // 144 int (1 KiB reserved)
#define WS_T1R   (WS_T1E + 1024ull)      // 144 int

static __device__ __forceinline__ u16 bf16rne(float f) {
  union { float f; uint32_t u; } c; c.f = f;
  return (u16)((c.u + 0x7FFFu + ((c.u >> 16) & 1u)) >> 16);
}

static __device__ __forceinline__ void load_lds16(const void* g, void* l) {
  __builtin_amdgcn_global_load_lds((const __attribute__((address_space(1))) void*)g,
                                   (__attribute__((address_space(3))) void*)l, 16, 0, 0);
}

// ---------------- gating + routing + x->bf16 ----------------
__global__ __launch_bounds__(256) void gate_kernel(
    const float* __restrict__ x, const float* __restrict__ gw,
    const float* __restrict__ gb, u16* __restrict__ xb,
    int* __restrict__ cnt, float* __restrict__ sump,
    int* __restrict__ list, float* __restrict__ pairw) {
  const int tid = threadIdx.x;
  const int lane = tid & 63;
  const int wv = tid >> 6;
  const int t = blockIdx.x * 4 + wv;

  __shared__ float sp[8];
  if (tid < 8) sp[tid] = 0.f;
  __syncthreads();

  float acc[8] = {0.f,0.f,0.f,0.f,0.f,0.f,0.f,0.f};
  const float4* x4 = (const float4*)x + (size_t)t * 256;
  u16x4* xb4 = (u16x4*)xb + (size_t)t * 256;
  #pragma unroll
  for (int it = 0; it < 4; ++it) {
    const float4 xv = x4[it * 64 + lane];
    u16x4 bv;
    bv[0] = bf16rne(xv.x); bv[1] = bf16rne(xv.y);
    bv[2] = bf16rne(xv.z); bv[3] = bf16rne(xv.w);
    xb4[it * 64 + lane] = bv;
    const int d0 = (it * 64 + lane) * 4;
    #pragma unroll
    for (int j = 0; j < 4; ++j) {
      const float xs = (j == 0) ? xv.x : ((j == 1) ? xv.y : ((j == 2) ? xv.z : xv.w));
      const float* g = gw + (size_t)(d0 + j) * 8;
      #pragma unroll
      for (int e2 = 0; e2 < 8; ++e2) acc[e2] += xs * g[e2];
    }
  }
  #pragma unroll
  for (int e2 = 0; e2 < 8; ++e2) {
    float v = acc[e2];
    v += __shfl_xor(v, 1);  v += __shfl_xor(v, 2);  v += __shfl_xor(v, 4);
    v += __shfl_xor(v, 8);  v += __shfl_xor(v, 16); v += __shfl_xor(v, 32);
    acc[e2] = v;
  }
  float p[8]; float mx = -1e30f;
  #pragma unroll
  for (int e2 = 0; e2 < 8; ++e2) { p[e2] = acc[e2] + gb[e2]; mx = fmaxf(mx, p[e2]); }
  float s = 0.f;
  #pragma unroll
  for (int e2 = 0; e2 < 8; ++e2) { p[e2] = expf(p[e2] - mx); s += p[e2]; }
  const float inv = 1.f / s;
  #pragma unroll
  for (int e2 = 0; e2 < 8; ++e2) p[e2] *= inv;

  if (lane == 0) {
    int i1 = 0; float v1 = p[0];
    #pragma unroll
    for (int e2 = 1; e2 < 8; ++e2) if (p[e2] > v1) { v1 = p[e2]; i1 = e2; }
    int i2 = 0; float v2 = -1.f;
    #pragma unroll
    for (int e2 = 0; e2 < 8; ++e2) if (e2 != i1 && p[e2] > v2) { v2 = p[e2]; i2 = e2; }
    const float den = v1 + v2 + 1e-6f;
    const int p1 = atomicAdd(&cnt[i1], 1);
    list[i1 * NTOK + p1] = t; pairw[i1 * NTOK + p1] = v1 / den;
    const int p2 = atomicAdd(&cnt[i2], 1);
    list[i2 * NTOK + p2] = t; pairw[i2 * NTOK + p2] = v2 / den;
    #pragma unroll
    for (int e2 = 0; e2 < 8; ++e2) atomicAdd(&sp[e2], p[e2]);
  }
  __syncthreads();
  if (tid < 8) atomicAdd(&sump[tid], sp[tid]);
}

// ---------------- fp32 [R][C] -> bf16 [C][R] transpose ----------------
__global__ __launch_bounds__(256) void conv_transpose(
    const float* __restrict__ in, u16* __restrict__ out, int R, int C) {
  __shared__ float tile[64][65];
  const int e = blockIdx.z;
  const float* pin = in + (size_t)e * R * C;
  u16* pout = out + (size_t)e * R * C;
  const int tx = threadIdx.x & 15;
  const int ty = threadIdx.x >> 4;
  const int c0 = blockIdx.x * 64;
  const int r0 = blockIdx.y * 64;
  #pragma unroll
  for (int i = 0; i < 4; ++i) {
    const int r = ty + i * 16;
    const float4 v = *(const float4*)(pin + (size_t)(r0 + r) * C + c0 + tx * 4);
    tile[r][tx * 4 + 0] = v.x;
    tile[r][tx * 4 + 1] = v.y;
    tile[r][tx * 4 + 2] = v.z;
    tile[r][tx * 4 + 3] = v.w;
  }
  __syncthreads();
  #pragma unroll
  for (int i = 0; i < 4; ++i) {
    const int c = ty + i * 16;
    u16x4 o;
    o[0] = bf16rne(tile[tx * 4 + 0][c]);
    o[1] = bf16rne(tile[tx * 4 + 1][c]);
    o[2] = bf16rne(tile[tx * 4 + 2][c]);
    o[3] = bf16rne(tile[tx * 4 + 3][c]);
    *(u16x4*)(pout + (size_t)(c0 + c) * R + r0 + tx * 4) = o;
  }
}

// ---------------- routing finalize: offsets, padding, 128-gran tile table ----------------
__global__ void route_finalize(const int* __restrict__ cnt, const float* __restrict__ sump,
                               int* __restrict__ padc, int* __restrict__ offs,
                               int* __restrict__ list, float* __restrict__ pairw,
                               int* __restrict__ t1e, int* __restrict__ t1r,
                               float* __restrict__ lb_out) {
  __shared__ int s_c[8], s_p[8];
  const int tid = threadIdx.x;
  if (tid == 0) {
    int o = 0; float lb = 0.f;
    for (int e = 0; e < 8; ++e) {
      const int c = cnt[e];
      const int pc = (c + 127) & ~127;
      s_c[e] = c; s_p[e] = pc;
      padc[e] = pc; offs[e] = o; o += pc;
      lb += ((float)c / 8192.f) * (sump[e] / 8192.f);
    }
    lb_out[0] = 0.01f * 8.f * lb;
    int n1 = 0;
    for (int e = 0; e < 8; ++e)
      for (int r = 0; r < s_p[e]; r += 128) { t1e[n1] = e; t1r[n1] = r; ++n1; }
    for (; n1 < NT1; ++n1) { t1e[n1] = -1; t1r[n1] = 0; }
  }
  __syncthreads();
  for (int e = 0; e < 8; ++e)
    for (int pq = s_c[e] + tid; pq < s_p[e]; pq += blockDim.x) {
      list[e * NTOK + pq] = 0; pairw[e * NTOK + pq] = 0.f;
    }
}

// ---------------- GEMM1: 128x128x32 m97-structure, dbuf LDS, fused SwiGLU ----------------
// 256 threads / 4 waves, 32 KiB LDS -> ~3 blocks/CU; overlap via block-level TLP (m114).
// Grid (j=64 fast, tt=144): XCD = j%8 -> per-XCD B working set 2 MB (L2-resident).
__global__ __launch_bounds__(256) void gemm1_kernel(
    const u16* __restrict__ xb, const u16* __restrict__ w1t,
    const float* __restrict__ b1, const int* __restrict__ list,
    const int* __restrict__ offs,
    const int* __restrict__ t1e, const int* __restrict__ t1r,
    u16* __restrict__ act) {
  const int tt = blockIdx.y;
  const int e = t1e[tt];
  if (e < 0) return;
  const int row0 = t1r[tt];
  const int j = blockIdx.x;
  const int off_e = offs[e];

  __shared__ u16 lds[16384];  // A: [buf][128][32] @0, B: same @8192 elems. 32 KiB.

  const int tid = threadIdx.x;
  const int lane = tid & 63;
  const int wv = tid >> 6;
  const int wr = wv >> 1, wc = wv & 1;
  const int l15 = lane & 15, l4 = lane >> 4;

  // staging: thread -> rows rt, rt+64; swizzled 16B source slot
  const int rt = tid >> 2;
  const int ce = ((tid & 3) ^ ((rt >> 1) & 3)) * 8;
  const int tok0 = list[e * NTOK + row0 + rt];
  const int tok1 = list[e * NTOK + row0 + rt + 64];
  const u16* srcA0 = xb + (size_t)tok0 * DDIM + ce;
  const u16* srcA1 = xb + (size_t)tok1 * DDIM + ce;
  const int rB1 = rt + 64;
  const int gn0 = j * 64 + (rt >> 5) * 16 + (rt & 15) + ((rt >> 4) & 1) * FDIM;
  const int gn1 = j * 64 + (rB1 >> 5) * 16 + (rB1 & 15) + ((rB1 >> 4) & 1) * FDIM;
  const u16* srcB0 = w1t + ((size_t)e * 2 * FDIM + gn0) * DDIM + ce;
  const u16* srcB1 = w1t + ((size_t)e * 2 * FDIM + gn1) * DDIM + ce;

  const int kel = (l4 ^ ((l15 >> 1) & 3)) * 8;
  const int aBase = (wr * 64 + l15) * 32 + kel;
  const int bBase = (wc * 64 + l15) * 32 + kel;

  f32x4 acc[4][4];
  #pragma unroll
  for (int m = 0; m < 4; ++m)
    #pragma unroll
    for (int n = 0; n < 4; ++n) { acc[m][n][0]=0.f; acc[m][n][1]=0.f; acc[m][n][2]=0.f; acc[m][n][3]=0.f; }

  #define STAGE1(buf, kt) do { \
    u16* _dA = &lds[(buf) * 4096 + wv * 512]; \
    u16* _dB = &lds[8192 + (buf) * 4096 + wv * 512]; \
    load_lds16(srcA0 + (kt) * 32, _dA); \
    load_lds16(srcA1 + (kt) * 32, _dA + 2048); \
    load_lds16(srcB0 + (kt) * 32, _dB); \
    load_lds16(srcB1 + (kt) * 32, _dB + 2048); \
  } while (0)

  STAGE1(0, 0);
  for (int kt = 0; kt < DDIM / 32; ++kt) {
    const int cur = kt & 1;
    __syncthreads();
    if (kt + 1 < DDIM / 32) STAGE1(cur ^ 1, kt + 1);
    bf16x8 aF[4], bF[4];
    #pragma unroll
    for (int m = 0; m < 4; ++m) aF[m] = *(const bf16x8*)&lds[cur * 4096 + aBase + m * 512];
    #pragma unroll
    for (int n = 0; n < 4; ++n) bF[n] = *(const bf16x8*)&lds[8192 + cur * 4096 + bBase + n * 512];
    #pragma unroll
    for (int m = 0; m < 4; ++m)
      #pragma unroll
      for (int n = 0; n < 4; ++n)
        acc[m][n] = __builtin_amdgcn_mfma_f32_16x16x32_bf16(aF[m], bF[n], acc[m][n], 0, 0, 0);
  }
  #undef STAGE1

  // epilogue: bias + SwiGLU (fast tanh-gelu) -> bf16 act
  const size_t actrow0 = (size_t)(off_e + row0);
  #pragma unroll
  for (int p2 = 0; p2 < 2; ++p2) {
    const int col = j * 64 + (wc * 2 + p2) * 16 + l15;
    const float ba = b1[e * (2 * FDIM) + col];
    const float bg = b1[e * (2 * FDIM) + FDIM + col];
    #pragma unroll
    for (int m = 0; m < 4; ++m) {
      #pragma unroll
      for (int jr = 0; jr < 4; ++jr) {
        const int row = wr * 64 + m * 16 + l4 * 4 + jr;
        const float a = acc[m][2 * p2][jr] + ba;
        const float g = acc[m][2 * p2 + 1][jr] + bg;
        const float u = 0.7978845608028654f * (g + 0.044715f * g * g * g);
        const float ex = __expf(2.f * u);
        const float th = 1.f - 2.f / (ex + 1.f);
        const float gg = 0.5f * g * (1.f + th);
        act[(actrow0 + row) * FDIM + col] = bf16rne(a * gg);
      }
    }
  }
}

// ---------------- GEMM2: 128x128x32 m97-structure; weighted atomic out ----------------
// 1D grid 1152: r=bid&7 (XCD), q=bid>>3, jt=q&7, tt=(q>>3)*8+r.
// Each XCD owns every-8th A-tile; a tile's 8 jt-blocks are temporally adjacent (A L2-hot).
__global__ __launch_bounds__(256) void gemm2_kernel(
    const u16* __restrict__ act, const u16* __restrict__ w2t,
    const float* __restrict__ b2, const int* __restrict__ list,
    const float* __restrict__ pairw, const int* __restrict__ offs,
    const int* __restrict__ t1e, const int* __restrict__ t1r,
    float* __restrict__ out) {
  const int bid = blockIdx.x;
  const int r8 = bid & 7;
  const int q = bid >> 3;
  const int jt = q & 7;
  const int tt = (q >> 3) * 8 + r8;
  const int e = t1e[tt];
  if (e < 0) return;
  const int row0 = t1r[tt];
  const int off_e = offs[e];

  __shared__ u16 lds[16384];

  const int tid = threadIdx.x;
  const int lane = tid & 63;
  const int wv = tid >> 6;
  const int wr = wv >> 1, wc = wv & 1;
  const int l15 = lane & 15, l4 = lane >> 4;

  const int rt = tid >> 2;
  const int ce = ((tid & 3) ^ ((rt >> 1) & 3)) * 8;
  const u16* srcA0 = act + (size_t)(off_e + row0 + rt) * FDIM + ce;
  const u16* srcA1 = act + (size_t)(off_e + row0 + rt + 64) * FDIM + ce;
  const u16* srcB0 = w2t + ((size_t)e * DDIM + jt * 128 + rt) * FDIM + ce;
  const u16* srcB1 = w2t + ((size_t)e * DDIM + jt * 128 + rt + 64) * FDIM + ce;

  const int kel = (l4 ^ ((l15 >> 1) & 3)) * 8;
  const int aBase = (wr * 64 + l15) * 32 + kel;
  const int bBase = (wc * 64 + l15) * 32 + kel;

  f32x4 acc[4][4];
  #pragma unroll
  for (int m = 0; m < 4; ++m)
    #pragma unroll
    for (int n = 0; n < 4; ++n) { acc[m][n][0]=0.f; acc[m][n][1]=0.f; acc[m][n][2]=0.f; acc[m][n][3]=0.f; }

  #define STAGE2(buf, kt) do { \
    u16* _dA = &lds[(buf) * 4096 + wv * 512]; \
    u16* _dB = &lds[8192 + (buf) * 4096 + wv * 512]; \
    load_lds16(srcA0 + (kt) * 32, _dA); \
    load_lds16(srcA1 + (kt) * 32, _dA + 2048); \
    load_lds16(srcB0 + (kt) * 32, _dB); \
    load_lds16(srcB1 + (kt) * 32, _dB + 2048); \
  } while (0)

  STAGE2(0, 0);
  for (int kt = 0; kt < FDIM / 32; ++kt) {
    const int cur = kt & 1;
    __syncthreads();
    if (kt + 1 < FDIM / 32) STAGE2(cur ^ 1, kt + 1);
    bf16x8 aF[4], bF[4];
    #pragma unroll
    for (int m = 0; m < 4; ++m) aF[m] = *(const bf16x8*)&lds[cur * 4096 + aBase + m * 512];
    #pragma unroll
    for (int n = 0; n < 4; ++n) bF[n] = *(const bf16x8*)&lds[8192 + cur * 4096 + bBase + n * 512];
    #pragma unroll
    for (int m = 0; m < 4; ++m)
      #pragma unroll
      for (int n = 0; n < 4; ++n)
        acc[m][n] = __builtin_amdgcn_mfma_f32_16x16x32_bf16(aF[m], bF[n], acc[m][n], 0, 0, 0);
  }
  #undef STAGE2

  // epilogue: weighted atomic accumulation into out
  #pragma unroll
  for (int m = 0; m < 4; ++m) {
    #pragma unroll
    for (int jr = 0; jr < 4; ++jr) {
      const int row = wr * 64 + m * 16 + l4 * 4 + jr;
      const int pos = row0 + row;
      const int tok = list[e * NTOK + pos];
      const float pw = pairw[e * NTOK + pos];
      if (pw != 0.f) {
        #pragma unroll
        for (int n = 0; n < 4; ++n) {
          const int col = jt * 128 + wc * 64 + n * 16 + l15;
          const float v = (acc[m][n][jr] + b2[e * DDIM + col]) * pw;
          atomicAdd(&out[(size_t)tok * DDIM + col], v);
        }
      }
    }
  }
}

extern "C" void kernel_launch(void* const* d_in, const int* in_sizes, int n_in,
                              void* d_out, int out_size, void* d_ws, size_t ws_size,
                              hipStream_t stream) {
  const float* x   = (const float*)d_in[0];
  const float* gw  = (const float*)d_in[1];
  const float* gb  = (const float*)d_in[2];
  const float* f1w = (const float*)d_in[3];
  const float* f1b = (const float*)d_in[4];
  const float* f2w = (const float*)d_in[5];
  const float* f2b = (const float*)d_in[6];
  float* out = (float*)d_out;
  char* ws = (char*)d_ws;

  u16*   xb    = (u16*)(ws + WS_XB);
  u16*   w1t   = (u16*)(ws + WS_W1T);
  u16*   w2t   = (u16*)(ws + WS_W2T);
  u16*   act   = (u16*)(ws + WS_ACT);
  int*   list  = (int*)(ws + WS_LIST);
  float* pairw = (float*)(ws + WS_PAIRW);
  int*   cnt   = (int*)(ws + WS_CNT);
  float* sump  = (float*)(ws + WS_SUMP);
  int*   padc  = (int*)(ws + WS_PAD);
  int*   offs  = (int*)(ws + WS_OFF);
  int*   t1e   = (int*)(ws + WS_T1E);
  int*   t1r   = (int*)(ws + WS_T1R);

  (void)hipMemsetAsync(d_out, 0, (size_t)out_size * sizeof(float), stream);
  (void)hipMemsetAsync(ws + WS_CNT, 0, 64, stream);  // cnt + sump

  gate_kernel<<<NTOK / 4, 256, 0, stream>>>(x, gw, gb, xb, cnt, sump, list, pairw);
  conv_transpose<<<dim3(8192 / 64, 1024 / 64, 8), 256, 0, stream>>>(f1w, w1t, 1024, 8192);
  conv_transpose<<<dim3(1024 / 64, 4096 / 64, 8), 256, 0, stream>>>(f2w, w2t, 4096, 1024);
  route_finalize<<<1, 256, 0, stream>>>(cnt, sump, padc, offs, list, pairw,
                                        t1e, t1r, out + 8388608);
  gemm1_kernel<<<dim3(64, NT1), 256, 0, stream>>>(xb, w1t, f1b, list, offs, t1e, t1r, act);
  gemm2_kernel<<<NT1 * 8, 256, 0, stream>>>(act, w2t, f2b, list, pairw, offs, t1e, t1r, out);
}

// Round 10
// 996.409 us; speedup vs baseline: 1.1635x; 1.0153x over previous
//
#include <hip/hip_runtime.h>
#include <hip/hip_bf16.h>
#include <stdint.h>

typedef __attribute__((ext_vector_type(4))) float f32x4;
typedef __attribute__((ext_vector_type(16))) float f32x16;
typedef __attribute__((ext_vector_type(8))) __bf16 bf16x8;
typedef __attribute__((ext_vector_type(4))) unsigned short u16x4;
typedef unsigned short u16;

#define NTOK 8192
#define DDIM 1024
#define FDIM 4096
#define NEXP 8
#define NT1 144

// ---- workspace layout (bytes) ----
#define WS_XB    0ull
#define WS_W1T   (16777216ull)
#define WS_W2T   (WS_W1T + 134217728ull)
#define WS_ACT   (WS_W2T + 67108864ull)
#define WS_LIST  (WS_ACT + 142606336ull)
#define WS_PAIRW (WS_LIST + 262144ull)
#define WS_CNT   (WS_PAIRW + 262144ull)
#define WS_SUMP  (WS_CNT + 32ull)
#define WS_PAD   (WS_SUMP + 32ull)
#define WS_OFF   (WS_PAD + 32ull)
#define WS_T1E   (WS_OFF + 32ull)        // 144 int (1 KiB reserved)
#define WS_T1R   (WS_T1E + 1024ull)      // 144 int

static __device__ __forceinline__ u16 bf16rne(float f) {
  union { float f; uint32_t u; } c; c.f = f;
  return (u16)((c.u + 0x7FFFu + ((c.u >> 16) & 1u)) >> 16);
}

static __device__ __forceinline__ void load_lds16(const void* g, void* l) {
  __builtin_amdgcn_global_load_lds((const __attribute__((address_space(1))) void*)g,
                                   (__attribute__((address_space(3))) void*)l, 16, 0, 0);
}

// ---------------- gating + routing + x->bf16 ----------------
__global__ __launch_bounds__(256) void gate_kernel(
    const float* __restrict__ x, const float* __restrict__ gw,
    const float* __restrict__ gb, u16* __restrict__ xb,
    int* __restrict__ cnt, float* __restrict__ sump,
    int* __restrict__ list, float* __restrict__ pairw) {
  const int tid = threadIdx.x;
  const int lane = tid & 63;
  const int wv = tid >> 6;
  const int t = blockIdx.x * 4 + wv;

  __shared__ float sp[8];
  if (tid < 8) sp[tid] = 0.f;
  __syncthreads();

  float acc[8] = {0.f,0.f,0.f,0.f,0.f,0.f,0.f,0.f};
  const float4* x4 = (const float4*)x + (size_t)t * 256;
  u16x4* xb4 = (u16x4*)xb + (size_t)t * 256;
  #pragma unroll
  for (int it = 0; it < 4; ++it) {
    const float4 xv = x4[it * 64 + lane];
    u16x4 bv;
    bv[0] = bf16rne(xv.x); bv[1] = bf16rne(xv.y);
    bv[2] = bf16rne(xv.z); bv[3] = bf16rne(xv.w);
    xb4[it * 64 + lane] = bv;
    const int d0 = (it * 64 + lane) * 4;
    #pragma unroll
    for (int j = 0; j < 4; ++j) {
      const float xs = (j == 0) ? xv.x : ((j == 1) ? xv.y : ((j == 2) ? xv.z : xv.w));
      const float* g = gw + (size_t)(d0 + j) * 8;
      #pragma unroll
      for (int e2 = 0; e2 < 8; ++e2) acc[e2] += xs * g[e2];
    }
  }
  #pragma unroll
  for (int e2 = 0; e2 < 8; ++e2) {
    float v = acc[e2];
    v += __shfl_xor(v, 1);  v += __shfl_xor(v, 2);  v += __shfl_xor(v, 4);
    v += __shfl_xor(v, 8);  v += __shfl_xor(v, 16); v += __shfl_xor(v, 32);
    acc[e2] = v;
  }
  float p[8]; float mx = -1e30f;
  #pragma unroll
  for (int e2 = 0; e2 < 8; ++e2) { p[e2] = acc[e2] + gb[e2]; mx = fmaxf(mx, p[e2]); }
  float s = 0.f;
  #pragma unroll
  for (int e2 = 0; e2 < 8; ++e2) { p[e2] = expf(p[e2] - mx); s += p[e2]; }
  const float inv = 1.f / s;
  #pragma unroll
  for (int e2 = 0; e2 < 8; ++e2) p[e2] *= inv;

  if (lane == 0) {
    int i1 = 0; float v1 = p[0];
    #pragma unroll
    for (int e2 = 1; e2 < 8; ++e2) if (p[e2] > v1) { v1 = p[e2]; i1 = e2; }
    int i2 = 0; float v2 = -1.f;
    #pragma unroll
    for (int e2 = 0; e2 < 8; ++e2) if (e2 != i1 && p[e2] > v2) { v2 = p[e2]; i2 = e2; }
    const float den = v1 + v2 + 1e-6f;
    const int p1 = atomicAdd(&cnt[i1], 1);
    list[i1 * NTOK + p1] = t; pairw[i1 * NTOK + p1] = v1 / den;
    const int p2 = atomicAdd(&cnt[i2], 1);
    list[i2 * NTOK + p2] = t; pairw[i2 * NTOK + p2] = v2 / den;
    #pragma unroll
    for (int e2 = 0; e2 < 8; ++e2) atomicAdd(&sp[e2], p[e2]);
  }
  __syncthreads();
  if (tid < 8) atomicAdd(&sump[tid], sp[tid]);
}

// ---------------- fp32 [R][C] -> bf16 [C][R] transpose ----------------
__global__ __launch_bounds__(256) void conv_transpose(
    const float* __restrict__ in, u16* __restrict__ out, int R, int C) {
  __shared__ float tile[64][65];
  const int e = blockIdx.z;
  const float* pin = in + (size_t)e * R * C;
  u16* pout = out + (size_t)e * R * C;
  const int tx = threadIdx.x & 15;
  const int ty = threadIdx.x >> 4;
  const int c0 = blockIdx.x * 64;
  const int r0 = blockIdx.y * 64;
  #pragma unroll
  for (int i = 0; i < 4; ++i) {
    const int r = ty + i * 16;
    const float4 v = *(const float4*)(pin + (size_t)(r0 + r) * C + c0 + tx * 4);
    tile[r][tx * 4 + 0] = v.x;
    tile[r][tx * 4 + 1] = v.y;
    tile[r][tx * 4 + 2] = v.z;
    tile[r][tx * 4 + 3] = v.w;
  }
  __syncthreads();
  #pragma unroll
  for (int i = 0; i < 4; ++i) {
    const int c = ty + i * 16;
    u16x4 o;
    o[0] = bf16rne(tile[tx * 4 + 0][c]);
    o[1] = bf16rne(tile[tx * 4 + 1][c]);
    o[2] = bf16rne(tile[tx * 4 + 2][c]);
    o[3] = bf16rne(tile[tx * 4 + 3][c]);
    *(u16x4*)(pout + (size_t)(c0 + c) * R + r0 + tx * 4) = o;
  }
}

// ---------------- routing finalize: offsets, padding, 128-gran tile table ----------------
__global__ void route_finalize(const int* __restrict__ cnt, const float* __restrict__ sump,
                               int* __restrict__ padc, int* __restrict__ offs,
                               int* __restrict__ list, float* __restrict__ pairw,
                               int* __restrict__ t1e, int* __restrict__ t1r,
                               float* __restrict__ lb_out) {
  __shared__ int s_c[8], s_p[8];
  const int tid = threadIdx.x;
  if (tid == 0) {
    int o = 0; float lb = 0.f;
    for (int e = 0; e < 8; ++e) {
      const int c = cnt[e];
      const int pc = (c + 127) & ~127;
      s_c[e] = c; s_p[e] = pc;
      padc[e] = pc; offs[e] = o; o += pc;
      lb += ((float)c / 8192.f) * (sump[e] / 8192.f);
    }
    lb_out[0] = 0.01f * 8.f * lb;
    int n1 = 0;
    for (int e = 0; e < 8; ++e)
      for (int r = 0; r < s_p[e]; r += 128) { t1e[n1] = e; t1r[n1] = r; ++n1; }
    for (; n1 < NT1; ++n1) { t1e[n1] = -1; t1r[n1] = 0; }
  }
  __syncthreads();
  for (int e = 0; e < 8; ++e)
    for (int pq = s_c[e] + tid; pq < s_p[e]; pq += blockDim.x) {
      list[e * NTOK + pq] = 0; pairw[e * NTOK + pq] = 0.f;
    }
}

// ---------------- GEMM1: 128x128x32 m97-structure, 32x32x16 MFMA, fused SwiGLU ----------------
// B rows interleave 32-col a/g groups: r 0-31 -> a[0..31], 32-63 -> g[0..31],
// 64-95 -> a[32..63], 96-127 -> g[32..63]  => acc[m][0]=a, acc[m][1]=g in-lane.
__global__ __launch_bounds__(256) void gemm1_kernel(
    const u16* __restrict__ xb, const u16* __restrict__ w1t,
    const float* __restrict__ b1, const int* __restrict__ list,
    const int* __restrict__ offs,
    const int* __restrict__ t1e, const int* __restrict__ t1r,
    u16* __restrict__ act) {
  const int tt = blockIdx.y;
  const int e = t1e[tt];
  if (e < 0) return;
  const int row0 = t1r[tt];
  const int j = blockIdx.x;
  const int off_e = offs[e];

  __shared__ u16 lds[16384];  // A: [buf][128][32] @0, B: same @8192 elems. 32 KiB.

  const int tid = threadIdx.x;
  const int lane = tid & 63;
  const int wv = tid >> 6;
  const int wr = wv >> 1, wc = wv & 1;
  const int l31 = lane & 31, s5 = lane >> 5;

  // staging: thread -> rows rt, rt+64; swizzled 16B source slot
  const int rt = tid >> 2;
  const int ce = ((tid & 3) ^ ((rt >> 1) & 3)) * 8;
  const int tok0 = list[e * NTOK + row0 + rt];
  const int tok1 = list[e * NTOK + row0 + rt + 64];
  const u16* srcA0 = xb + (size_t)tok0 * DDIM + ce;
  const u16* srcA1 = xb + (size_t)tok1 * DDIM + ce;
  const int rB1 = rt + 64;
  const int gn0 = j * 64 + ((rt >> 6) & 1) * 32 + (rt & 31) + ((rt >> 5) & 1) * FDIM;
  const int gn1 = j * 64 + ((rB1 >> 6) & 1) * 32 + (rB1 & 31) + ((rB1 >> 5) & 1) * FDIM;
  const u16* srcB0 = w1t + ((size_t)e * 2 * FDIM + gn0) * DDIM + ce;
  const u16* srcB1 = w1t + ((size_t)e * 2 * FDIM + gn1) * DDIM + ce;

  // ds_read bases: k-slot (ks*2 + s5) ^ ((row>>1)&3), row = l31-based
  const int xsw = (l31 >> 1) & 3;
  const int kel0 = (s5 ^ xsw) * 8;
  const int aB0 = (wr * 64 + l31) * 32 + kel0;  const int aB1 = aB0 ^ 16;
  const int bB0 = (wc * 64 + l31) * 32 + kel0;  const int bB1 = bB0 ^ 16;

  f32x16 acc[2][2];
  #pragma unroll
  for (int m = 0; m < 2; ++m)
    #pragma unroll
    for (int n = 0; n < 2; ++n)
      #pragma unroll
      for (int i = 0; i < 16; ++i) acc[m][n][i] = 0.f;

  #define STAGE1(buf, kt) do { \
    u16* _dA = &lds[(buf) * 4096 + wv * 512]; \
    u16* _dB = &lds[8192 + (buf) * 4096 + wv * 512]; \
    load_lds16(srcA0 + (kt) * 32, _dA); \
    load_lds16(srcA1 + (kt) * 32, _dA + 2048); \
    load_lds16(srcB0 + (kt) * 32, _dB); \
    load_lds16(srcB1 + (kt) * 32, _dB + 2048); \
  } while (0)

  STAGE1(0, 0);
  for (int kt = 0; kt < DDIM / 32; ++kt) {
    const int cur = kt & 1;
    __syncthreads();
    if (kt + 1 < DDIM / 32) STAGE1(cur ^ 1, kt + 1);
    const int bA = cur * 4096;
    const int bB = 8192 + cur * 4096;
    bf16x8 a0[2], a1[2], Bh0[2], Bh1[2];
    #pragma unroll
    for (int m = 0; m < 2; ++m) {
      a0[m] = *(const bf16x8*)&lds[bA + aB0 + m * 1024];
      a1[m] = *(const bf16x8*)&lds[bA + aB1 + m * 1024];
    }
    #pragma unroll
    for (int n = 0; n < 2; ++n) {
      Bh0[n] = *(const bf16x8*)&lds[bB + bB0 + n * 1024];
      Bh1[n] = *(const bf16x8*)&lds[bB + bB1 + n * 1024];
    }
    #pragma unroll
    for (int m = 0; m < 2; ++m)
      #pragma unroll
      for (int n = 0; n < 2; ++n) {
        acc[m][n] = __builtin_amdgcn_mfma_f32_32x32x16_bf16(a0[m], Bh0[n], acc[m][n], 0, 0, 0);
        acc[m][n] = __builtin_amdgcn_mfma_f32_32x32x16_bf16(a1[m], Bh1[n], acc[m][n], 0, 0, 0);
      }
  }
  #undef STAGE1

  // epilogue: bias + SwiGLU (sigmoid-form gelu) -> bf16 act
  const size_t actrow0 = (size_t)(off_e + row0);
  const int col = j * 64 + wc * 32 + l31;
  const float ba = b1[e * (2 * FDIM) + col];
  const float bg = b1[e * (2 * FDIM) + FDIM + col];
  #pragma unroll
  for (int m = 0; m < 2; ++m) {
    #pragma unroll
    for (int r = 0; r < 16; ++r) {
      const int row = wr * 64 + m * 32 + (r & 3) + 8 * (r >> 2) + 4 * s5;
      const float a = acc[m][0][r] + ba;
      const float g = acc[m][1][r] + bg;
      const float u2 = 1.5957691216057308f * (g + 0.044715f * g * g * g);
      const float sg = 1.f / (1.f + __expf(-u2));
      act[(actrow0 + row) * FDIM + col] = bf16rne(a * g * sg);
    }
  }
}

// ---------------- GEMM2: 128x128x32 m97-structure, 32x32x16 MFMA; atomic out ----------------
// 1D grid 1152: r=bid&7 (XCD), q=bid>>3, jt=q&7, tt=(q>>3)*8+r.
__global__ __launch_bounds__(256) void gemm2_kernel(
    const u16* __restrict__ act, const u16* __restrict__ w2t,
    const float* __restrict__ b2, const int* __restrict__ list,
    const float* __restrict__ pairw, const int* __restrict__ offs,
    const int* __restrict__ t1e, const int* __restrict__ t1r,
    float* __restrict__ out) {
  const int bid = blockIdx.x;
  const int r8 = bid & 7;
  const int q = bid >> 3;
  const int jt = q & 7;
  const int tt = (q >> 3) * 8 + r8;
  const int e = t1e[tt];
  if (e < 0) return;
  const int row0 = t1r[tt];
  const int off_e = offs[e];

  __shared__ u16 lds[16384];

  const int tid = threadIdx.x;
  const int lane = tid & 63;
  const int wv = tid >> 6;
  const int wr = wv >> 1, wc = wv & 1;
  const int l31 = lane & 31, s5 = lane >> 5;

  const int rt = tid >> 2;
  const int ce = ((tid & 3) ^ ((rt >> 1) & 3)) * 8;
  const u16* srcA0 = act + (size_t)(off_e + row0 + rt) * FDIM + ce;
  const u16* srcA1 = act + (size_t)(off_e + row0 + rt + 64) * FDIM + ce;
  const u16* srcB0 = w2t + ((size_t)e * DDIM + jt * 128 + rt) * FDIM + ce;
  const u16* srcB1 = w2t + ((size_t)e * DDIM + jt * 128 + rt + 64) * FDIM + ce;

  const int xsw = (l31 >> 1) & 3;
  const int kel0 = (s5 ^ xsw) * 8;
  const int aB0 = (wr * 64 + l31) * 32 + kel0;  const int aB1 = aB0 ^ 16;
  const int bB0 = (wc * 64 + l31) * 32 + kel0;  const int bB1 = bB0 ^ 16;

  f32x16 acc[2][2];
  #pragma unroll
  for (int m = 0; m < 2; ++m)
    #pragma unroll
    for (int n = 0; n < 2; ++n)
      #pragma unroll
      for (int i = 0; i < 16; ++i) acc[m][n][i] = 0.f;

  #define STAGE2(buf, kt) do { \
    u16* _dA = &lds[(buf) * 4096 + wv * 512]; \
    u16* _dB = &lds[8192 + (buf) * 4096 + wv * 512]; \
    load_lds16(srcA0 + (kt) * 32, _dA); \
    load_lds16(srcA1 + (kt) * 32, _dA + 2048); \
    load_lds16(srcB0 + (kt) * 32, _dB); \
    load_lds16(srcB1 + (kt) * 32, _dB + 2048); \
  } while (0)

  STAGE2(0, 0);
  for (int kt = 0; kt < FDIM / 32; ++kt) {
    const int cur = kt & 1;
    __syncthreads();
    if (kt + 1 < FDIM / 32) STAGE2(cur ^ 1, kt + 1);
    const int bA = cur * 4096;
    const int bB = 8192 + cur * 4096;
    bf16x8 a0[2], a1[2], Bh0[2], Bh1[2];
    #pragma unroll
    for (int m = 0; m < 2; ++m) {
      a0[m] = *(const bf16x8*)&lds[bA + aB0 + m * 1024];
      a1[m] = *(const bf16x8*)&lds[bA + aB1 + m * 1024];
    }
    #pragma unroll
    for (int n = 0; n < 2; ++n) {
      Bh0[n] = *(const bf16x8*)&lds[bB + bB0 + n * 1024];
      Bh1[n] = *(const bf16x8*)&lds[bB + bB1 + n * 1024];
    }
    #pragma unroll
    for (int m = 0; m < 2; ++m)
      #pragma unroll
      for (int n = 0; n < 2; ++n) {
        acc[m][n] = __builtin_amdgcn_mfma_f32_32x32x16_bf16(a0[m], Bh0[n], acc[m][n], 0, 0, 0);
        acc[m][n] = __builtin_amdgcn_mfma_f32_32x32x16_bf16(a1[m], Bh1[n], acc[m][n], 0, 0, 0);
      }
  }
  #undef STAGE2

  // epilogue: weighted atomic accumulation into out
  #pragma unroll
  for (int m = 0; m < 2; ++m) {
    #pragma unroll
    for (int r = 0; r < 16; ++r) {
      const int row = wr * 64 + m * 32 + (r & 3) + 8 * (r >> 2) + 4 * s5;
      const int pos = row0 + row;
      const int tok = list[e * NTOK + pos];
      const float pw = pairw[e * NTOK + pos];
      if (pw != 0.f) {
        #pragma unroll
        for (int n = 0; n < 2; ++n) {
          const int col = jt * 128 + wc * 64 + n * 32 + l31;
          const float v = (acc[m][n][r] + b2[e * DDIM + col]) * pw;
          atomicAdd(&out[(size_t)tok * DDIM + col], v);
        }
      }
    }
  }
}

extern "C" void kernel_launch(void* const* d_in, const int* in_sizes, int n_in,
                              void* d_out, int out_size, void* d_ws, size_t ws_size,
                              hipStream_t stream) {
  const float* x   = (const float*)d_in[0];
  const float* gw  = (const float*)d_in[1];
  const float* gb  = (const float*)d_in[2];
  const float* f1w = (const float*)d_in[3];
  const float* f1b = (const float*)d_in[4];
  const float* f2w = (const float*)d_in[5];
  const float* f2b = (const float*)d_in[6];
  float* out = (float*)d_out;
  char* ws = (char*)d_ws;

  u16*   xb    = (u16*)(ws + WS_XB);
  u16*   w1t   = (u16*)(ws + WS_W1T);
  u16*   w2t   = (u16*)(ws + WS_W2T);
  u16*   act   = (u16*)(ws + WS_ACT);
  int*   list  = (int*)(ws + WS_LIST);
  float* pairw = (float*)(ws + WS_PAIRW);
  int*   cnt   = (int*)(ws + WS_CNT);
  float* sump  = (float*)(ws + WS_SUMP);
  int*   padc  = (int*)(ws + WS_PAD);
  int*   offs  = (int*)(ws + WS_OFF);
  int*   t1e   = (int*)(ws + WS_T1E);
  int*   t1r   = (int*)(ws + WS_T1R);

  (void)hipMemsetAsync(d_out, 0, (size_t)out_size * sizeof(float), stream);
  (void)hipMemsetAsync(ws + WS_CNT, 0, 64, stream);  // cnt + sump

  gate_kernel<<<NTOK / 4, 256, 0, stream>>>(x, gw, gb, xb, cnt, sump, list, pairw);
  conv_transpose<<<dim3(8192 / 64, 1024 / 64, 8), 256, 0, stream>>>(f1w, w1t, 1024, 8192);
  conv_transpose<<<dim3(1024 / 64, 4096 / 64, 8), 256, 0, stream>>>(f2w, w2t, 4096, 1024);
  route_finalize<<<1, 256, 0, stream>>>(cnt, sump, padc, offs, list, pairw,
                                        t1e, t1r, out + 8388608);
  gemm1_kernel<<<dim3(64, NT1), 256, 0, stream>>>(xb, w1t, f1b, list, offs, t1e, t1r, act);
  gemm2_kernel<<<NT1 * 8, 256, 0, stream>>>(act, w2t, f2b, list, pairw, offs, t1e, t1r, out);
}